// Round 1
// baseline (248.780 us; speedup 1.0000x reference)
//
#include <hip/hip_runtime.h>
#include <math.h>

// mask[i][j] = (j < block_end(i)) && (j != i), where
// block_end(i) = (i / n_nodes + 1) * n_nodes.
// Derivation: ((i>j) | same_block) & (i!=j)  ==  (j < block_end) & (j != i)
//   - j < i          -> i>j covers it (and j != i holds)
//   - j == i         -> masked off by (i != j)
//   - i < j < blkend -> same_block covers it
//   - j >= blkend    -> neither condition

__global__ void Create_Mask_23871428231714_kernel(const int* __restrict__ n_nodes_p,
                                                  float* __restrict__ out, int n) {
    const int n_nodes = *n_nodes_p;           // scalar, L2-cached broadcast
    const int i = blockIdx.y;                 // row
    const int j0 = (blockIdx.x * blockDim.x + threadIdx.x) << 2;
    if (j0 >= n) return;

    const int blk_end = (i / n_nodes + 1) * n_nodes;  // row-uniform

    float4 v;
    v.x = ((j0     < blk_end) && (j0     != i)) ? 1.0f : 0.0f;
    v.y = ((j0 + 1 < blk_end) && (j0 + 1 != i)) ? 1.0f : 0.0f;
    v.z = ((j0 + 2 < blk_end) && (j0 + 2 != i)) ? 1.0f : 0.0f;
    v.w = ((j0 + 3 < blk_end) && (j0 + 3 != i)) ? 1.0f : 0.0f;

    // n is a multiple of 4 (n = 64*128), j0 multiple of 4 -> 16B aligned
    *reinterpret_cast<float4*>(out + (size_t)i * (size_t)n + (size_t)j0) = v;
}

extern "C" void kernel_launch(void* const* d_in, const int* in_sizes, int n_in,
                              void* d_out, int out_size, void* d_ws, size_t ws_size,
                              hipStream_t stream) {
    (void)in_sizes; (void)n_in; (void)d_ws; (void)ws_size;
    const int* n_nodes_p = (const int*)d_in[0];
    float* out = (float*)d_out;

    // out is n x n -> recover n on host without any device readback
    const int n = (int)llround(sqrt((double)out_size));

    const int block = 256;                       // 4 waves
    const int elems_per_block = block * 4;       // float4 per thread
    dim3 grid((n + elems_per_block - 1) / elems_per_block, n, 1);
    Create_Mask_23871428231714_kernel<<<grid, dim3(block, 1, 1), 0, stream>>>(n_nodes_p, out, n);
}